// Round 2
// baseline (409.979 us; speedup 1.0000x reference)
//
#include <hip/hip_runtime.h>
#include <hip/hip_bf16.h>

typedef __attribute__((ext_vector_type(8))) short bf16x8;
typedef __attribute__((ext_vector_type(4))) float f32x4;

#define N_OBJ 1024
#define N_REL 1024
#define NB 32
#define D 512
#define VOCAB 2048
#define M_ROWS (NB * N_REL)          // 32768
#define PRE_BLK (VOCAB * D)          // 1048576 floats per PRE block
#define WT_BLK (D * D)               // 262144 elems per transposed weight block

__device__ __forceinline__ ushort f2bf(float f) {
    union { float f; unsigned u; } v; v.f = f;
    unsigned u = v.u;
    unsigned r = (u + 0x7FFFu + ((u >> 16) & 1u)) >> 16;
    return (ushort)r;
}
__device__ __forceinline__ float bf2f(ushort h) {
    union { unsigned u; float f; } v; v.u = ((unsigned)h) << 16;
    return v.f;
}

// ---------------- K0a: emb_table f32 -> bf16 ----------------
__global__ void k_cvt_emb(const float* __restrict__ E, ushort* __restrict__ EB) {
    int i = blockIdx.x * 256 + threadIdx.x;   // VOCAB*D = 1048576 elements
    EB[i] = f2bf(E[i]);
}

// ---------------- K0b: transpose weight 512x512 blocks to N x K bf16 ----------------
// WT block order: 0,1,2 = W_sbj k-blocks; 3,4,5 = W_obj; 6,7,8 = W_rel; 9 = W_o; 10,11 = W_a
__global__ void k_transpose_w(const float* __restrict__ Wsbj, const float* __restrict__ Wobj,
                              const float* __restrict__ Wrel, const float* __restrict__ Wo,
                              const float* __restrict__ Wa, ushort* __restrict__ WT) {
    __shared__ float s[32][33];
    int q = blockIdx.z;
    const float* src; int ro;
    if (q < 3)       { src = Wsbj; ro = q * 512; }
    else if (q < 6)  { src = Wobj; ro = (q - 3) * 512; }
    else if (q < 9)  { src = Wrel; ro = (q - 6) * 512; }
    else if (q == 9) { src = Wo;   ro = 0; }
    else             { src = Wa;   ro = (q - 10) * 512; }
    int tx = threadIdx.x, ty = threadIdx.y;        // 32 x 8
    int kbase = blockIdx.y * 32, nbase = blockIdx.x * 32;
#pragma unroll
    for (int i = 0; i < 4; i++) {
        int k = kbase + ty + i * 8;
        s[ty + i * 8][tx] = src[(size_t)(ro + k) * 512 + nbase + tx];
    }
    __syncthreads();
    ushort* dst = WT + (size_t)q * WT_BLK;
#pragma unroll
    for (int i = 0; i < 4; i++) {
        int n = nbase + ty + i * 8;
        dst[(size_t)n * 512 + kbase + tx] = f2bf(s[tx][ty + i * 8]);
    }
}

// ---------------- GEMM: C[128x128] tiles, bf16 MFMA 16x16x32, BK=32 ----------------
// MODE 0: PRE = EB @ WT[q]   (grid: 16 x 4 x 9), plain f32 store
// MODE 1: U = sbjf @ [Wobj0 | Wrel0]  (grid: 256 x 8)
//         cols<512 : obj_f epilogue (gather PRE_B2/B3 + bias, relu, mask, store bf16, atomic node)
//         cols>=512: store trel1 bf16 raw
// MODE 2: rel_f = relu(objf @ Wrel1 + trel1 + PRE_C3 + b_rel), masked -> out0 mid section (f32)
template <int MODE>
__global__ __launch_bounds__(256)
void k_gemm(const ushort* __restrict__ A, const ushort* __restrict__ WT,
            float* __restrict__ PRE,
            const int* __restrict__ ssg_rel, const int* __restrict__ ssg_obj,
            const float* __restrict__ bias,
            ushort* __restrict__ objf, ushort* __restrict__ trel1,
            float* __restrict__ node, float* __restrict__ out0) {
    constexpr int SAP = 40;   // padded LDS row stride (elems): 80B, 16B-aligned, 2-way banks
    __shared__ __attribute__((aligned(16))) ushort sA[128 * SAP];
    __shared__ __attribute__((aligned(16))) ushort sB[128 * SAP];

    const int tid = threadIdx.x;
    const int m0 = blockIdx.x * 128;
    const int y = blockIdx.y;

    const ushort* BTblk;
    float* PREq = nullptr;
    int cHalf = 0;
    if (MODE == 0) {
        const int wtq[9] = {0, 1, 2, 4, 5, 8, 9, 10, 11};
        int q = blockIdx.z;
        BTblk = WT + (size_t)wtq[q] * WT_BLK + (size_t)y * 128 * 512;
        PREq = PRE + (size_t)q * PRE_BLK;
    } else if (MODE == 1) {
        cHalf = (y >= 4);
        BTblk = WT + (size_t)(cHalf ? 6 : 3) * WT_BLK + (size_t)(y & 3) * 128 * 512;
    } else {
        BTblk = WT + (size_t)7 * WT_BLK + (size_t)y * 128 * 512;
    }

    const int wave = tid >> 6, lane = tid & 63;
    const int wm = wave >> 1, wn = wave & 1;
    const int lr = lane & 15, lk = lane >> 4;

    f32x4 acc[4][4];
#pragma unroll
    for (int mi = 0; mi < 4; mi++)
#pragma unroll
        for (int ni = 0; ni < 4; ni++)
            acc[mi][ni] = (f32x4){0.f, 0.f, 0.f, 0.f};

    const ushort* Ag = A + (size_t)m0 * 512;

    for (int k0 = 0; k0 < 512; k0 += 32) {
#pragma unroll
        for (int s = 0; s < 2; s++) {
            int li = s * 256 + tid;
            int row = li >> 2, cg = li & 3;
            *(int4*)&sA[row * SAP + cg * 8] = *(const int4*)&Ag[(size_t)row * 512 + k0 + cg * 8];
            *(int4*)&sB[row * SAP + cg * 8] = *(const int4*)&BTblk[(size_t)row * 512 + k0 + cg * 8];
        }
        __syncthreads();
        bf16x8 af[4], bfr[4];
#pragma unroll
        for (int mi = 0; mi < 4; mi++)
            af[mi] = *(const bf16x8*)&sA[(wm * 64 + mi * 16 + lr) * SAP + lk * 8];
#pragma unroll
        for (int ni = 0; ni < 4; ni++)
            bfr[ni] = *(const bf16x8*)&sB[(wn * 64 + ni * 16 + lr) * SAP + lk * 8];
#pragma unroll
        for (int mi = 0; mi < 4; mi++)
#pragma unroll
            for (int ni = 0; ni < 4; ni++)
                acc[mi][ni] = __builtin_amdgcn_mfma_f32_16x16x32_bf16(af[mi], bfr[ni], acc[mi][ni], 0, 0, 0);
        __syncthreads();
    }

    // ---- epilogue ----
    int* sIo  = (int*)sA;          // overlay (mainloop done, post-sync)
    int* sRid = sIo + 128;
    int* sOid = sRid + 128;
    if (MODE == 1 || MODE == 2) {
        if (tid < 128) {
            int R = m0 + tid;
            int oid = ssg_rel[R * 3 + 1];
            int rid = ssg_rel[R * 3 + 2];
            sOid[tid] = oid;
            sRid[tid] = rid;
            sIo[tid] = ssg_obj[(R & ~(N_OBJ - 1)) + oid];
        }
        __syncthreads();
    }

#pragma unroll
    for (int mi = 0; mi < 4; mi++) {
#pragma unroll
        for (int ni = 0; ni < 4; ni++) {
            int c = wn * 64 + ni * 16 + lr;   // local col 0..127
            int ch = (MODE == 1) ? ((y & 3) * 128 + c) : (y * 128 + c);
#pragma unroll
            for (int j = 0; j < 4; j++) {
                int rl = wm * 64 + mi * 16 + lk * 4 + j;
                int R = m0 + rl;
                float v = acc[mi][ni][j];
                if (MODE == 0) {
                    PREq[(size_t)R * 512 + ch] = v;
                } else if (MODE == 1) {
                    int rid = sRid[rl];
                    if (!cHalf) {
                        int io = sIo[rl];
                        float t = v + PRE[(size_t)3 * PRE_BLK + (size_t)io * 512 + ch]
                                    + PRE[(size_t)4 * PRE_BLK + (size_t)rid * 512 + ch]
                                    + bias[ch];
                        t = fmaxf(t, 0.f);
                        if (rid == 1) t = 0.f;
                        objf[(size_t)R * 512 + ch] = f2bf(t);
                        if (t != 0.f) {
                            int oid = sOid[rl];
                            atomicAdd(&node[(size_t)((R & ~(N_OBJ - 1)) + oid) * 512 + ch], t);
                        }
                    } else {
                        trel1[(size_t)R * 512 + ch] = f2bf(v);
                    }
                } else {  // MODE 2
                    int rid = sRid[rl];
                    float t = v + bf2f(trel1[(size_t)R * 512 + ch])
                                + PRE[(size_t)5 * PRE_BLK + (size_t)rid * 512 + ch]
                                + bias[ch];
                    t = fmaxf(t, 0.f);
                    if (rid == 1) t = 0.f;
                    int b = R >> 10, rr = R & (N_REL - 1);
                    out0[((size_t)(b * 3072 + 1024 + rr)) * 512 + ch] = t;
                }
            }
        }
    }
}

// ---------------- node init: node = masked relu(Q[ssg_obj] + b_o) ----------------
__global__ void k_node_init(const int* __restrict__ ssg_obj, const float* __restrict__ PRE,
                            const float* __restrict__ b_o, float* __restrict__ node) {
    int Ro = blockIdx.x;                     // b*1024 + o
    int iv = ssg_obj[Ro];
    const float* Q = PRE + (size_t)6 * PRE_BLK + (size_t)iv * 512;
    bool msk = (iv == 1);
    for (int c = threadIdx.x; c < 512; c += 256) {
        float v = fmaxf(Q[c] + b_o[c], 0.f);
        node[(size_t)Ro * 512 + c] = msk ? 0.f : v;
    }
}

// ---------------- sbj_f: table lookup layer + scatter into node ----------------
__global__ void k_sbj(const int* __restrict__ ssg_rel, const int* __restrict__ ssg_obj,
                      const float* __restrict__ PRE, const float* __restrict__ b_sbj,
                      ushort* __restrict__ sbjf, float* __restrict__ node) {
    int R = blockIdx.x;                      // 0..32767
    int sid = ssg_rel[R * 3 + 0];
    int oid = ssg_rel[R * 3 + 1];
    int rid = ssg_rel[R * 3 + 2];
    int bb = R & ~(N_OBJ - 1);
    int is_ = ssg_obj[bb + sid];
    int io  = ssg_obj[bb + oid];
    const float* P1 = PRE + (size_t)is_ * 512;
    const float* P2 = PRE + (size_t)1 * PRE_BLK + (size_t)io * 512;
    const float* P3 = PRE + (size_t)2 * PRE_BLK + (size_t)rid * 512;
    bool msk = (rid == 1);
    for (int c = threadIdx.x; c < 512; c += 256) {
        float v = P1[c] + P2[c] + P3[c] + b_sbj[c];
        v = fmaxf(v, 0.f);
        if (msk) v = 0.f;
        sbjf[(size_t)R * 512 + c] = f2bf(v);
        if (v != 0.f) atomicAdd(&node[(size_t)(bb + sid) * 512 + c], v);
    }
}

// ---------------- node -> out (rel_object_feat = node / 2048) ----------------
__global__ void k_node_out(const float* __restrict__ node, float* __restrict__ out0) {
    int i = blockIdx.x * 256 + threadIdx.x;  // 32*1024*512 = 16.8M
    int Ro = i >> 9, c = i & 511;
    int b = Ro >> 10, o = Ro & (N_OBJ - 1);
    out0[((size_t)(b * 3072 + o)) * 512 + c] = node[(size_t)i] * (1.0f / 2048.0f);
}

// ---------------- att features ----------------
__global__ void k_att(const int* __restrict__ ssg_obj, const int* __restrict__ ssg_att,
                      const float* __restrict__ PRE, const float* __restrict__ b_a,
                      float* __restrict__ out0) {
    int Ro = blockIdx.x;
    int iv = ssg_obj[Ro];
    int j0 = ssg_att[Ro * 4 + 0], j1 = ssg_att[Ro * 4 + 1];
    int j2 = ssg_att[Ro * 4 + 2], j3 = ssg_att[Ro * 4 + 3];
    const float* A1 = PRE + (size_t)7 * PRE_BLK + (size_t)iv * 512;
    const float* A2 = PRE + (size_t)8 * PRE_BLK;
    int cnt = (j0 != 1) + (j1 != 1) + (j2 != 1) + (j3 != 1);
    float inv = cnt ? 1.0f / (float)cnt : 0.f;
    int b = Ro >> 10, o = Ro & (N_OBJ - 1);
    float* dst = out0 + ((size_t)(b * 3072 + 2048 + o)) * 512;
    for (int c = threadIdx.x; c < 512; c += 256) {
        float base = A1[c] + b_a[c];
        float s = 0.f;
        if (j0 != 1) s += fmaxf(base + A2[(size_t)j0 * 512 + c], 0.f);
        if (j1 != 1) s += fmaxf(base + A2[(size_t)j1 * 512 + c], 0.f);
        if (j2 != 1) s += fmaxf(base + A2[(size_t)j2 * 512 + c], 0.f);
        if (j3 != 1) s += fmaxf(base + A2[(size_t)j3 * 512 + c], 0.f);
        dst[c] = s * inv;
    }
}

// ---------------- masks ----------------
__global__ void k_mask(const int* __restrict__ ssg_rel, const int* __restrict__ ssg_obj,
                       const int* __restrict__ ssg_att, float* __restrict__ out1) {
    int i = blockIdx.x * 256 + threadIdx.x;
    if (i >= NB * 3072) return;
    int b = i / 3072, j = i % 3072;
    bool m;
    if (j < 1024) m = (ssg_obj[b * 1024 + j] == 1);
    else if (j < 2048) m = (ssg_rel[(b * 1024 + (j - 1024)) * 3 + 2] == 1);
    else {
        const int* p = ssg_att + (size_t)(b * 1024 + (j - 2048)) * 4;
        m = (p[0] == 1) && (p[1] == 1) && (p[2] == 1) && (p[3] == 1);
    }
    out1[i] = m ? 1.0f : 0.0f;
}

extern "C" void kernel_launch(void* const* d_in, const int* in_sizes, int n_in,
                              void* d_out, int out_size, void* d_ws, size_t ws_size,
                              hipStream_t stream) {
    const int*   ssg_rel = (const int*)d_in[0];
    const int*   ssg_obj = (const int*)d_in[1];
    const int*   ssg_att = (const int*)d_in[2];
    const float* emb     = (const float*)d_in[3];
    const float* Wsbj    = (const float*)d_in[4];
    const float* bsbj    = (const float*)d_in[5];
    const float* Wobj    = (const float*)d_in[6];
    const float* bobj    = (const float*)d_in[7];
    const float* Wrel    = (const float*)d_in[8];
    const float* brel    = (const float*)d_in[9];
    const float* Wo      = (const float*)d_in[10];
    const float* bo      = (const float*)d_in[11];
    const float* Wa      = (const float*)d_in[12];
    const float* ba      = (const float*)d_in[13];

    float* out0 = (float*)d_out;
    float* out1 = out0 + (size_t)NB * 3072 * 512;   // 50331648 floats

    char* w = (char*)d_ws;
    ushort* EB   = (ushort*)w; w += (size_t)VOCAB * D * 2;            //  2.0 MB
    ushort* WT   = (ushort*)w; w += (size_t)12 * WT_BLK * 2;          //  6.3 MB
    float*  PRE  = (float*) w; w += (size_t)9 * PRE_BLK * 4;          // 37.7 MB
    ushort* sbjf = (ushort*)w; w += (size_t)M_ROWS * D * 2;           // 33.6 MB
    ushort* objf = (ushort*)w; w += (size_t)M_ROWS * D * 2;           // 33.6 MB
    ushort* trl1 = (ushort*)w; w += (size_t)M_ROWS * D * 2;           // 33.6 MB
    float*  node = (float*) w; w += (size_t)M_ROWS * D * 4;           // 67.1 MB

    // 1) converts / transposes
    k_cvt_emb<<<dim3(VOCAB * D / 256), dim3(256), 0, stream>>>(emb, EB);
    k_transpose_w<<<dim3(16, 16, 12), dim3(32, 8), 0, stream>>>(Wsbj, Wobj, Wrel, Wo, Wa, WT);
    // 2) PRE = E @ {9 weight blocks}
    k_gemm<0><<<dim3(16, 4, 9), dim3(256), 0, stream>>>(EB, WT, PRE, ssg_rel, ssg_obj,
                                                        nullptr, nullptr, nullptr, nullptr, nullptr);
    // 3) node init (needs PRE q6)
    k_node_init<<<dim3(NB * N_OBJ), dim3(256), 0, stream>>>(ssg_obj, PRE, bo, node);
    // 4) sbj_f lookup layer + scatter
    k_sbj<<<dim3(M_ROWS), dim3(256), 0, stream>>>(ssg_rel, ssg_obj, PRE, bsbj, sbjf, node);
    // 5) U = sbjf @ [Wobj0 | Wrel0]; obj_f epilogue + scatter; trel1 raw
    k_gemm<1><<<dim3(M_ROWS / 128, 8), dim3(256), 0, stream>>>(sbjf, WT, PRE, ssg_rel, ssg_obj,
                                                               bobj, objf, trl1, node, nullptr);
    // 6) rel_f = relu(objf @ Wrel1 + trel1 + C3 + b_rel) -> out (f32)
    k_gemm<2><<<dim3(M_ROWS / 128, 4), dim3(256), 0, stream>>>(objf, WT, PRE, ssg_rel, ssg_obj,
                                                               brel, nullptr, trl1, nullptr, out0);
    // 7) rel_object_feat = node / 2048 -> out (f32)
    k_node_out<<<dim3(M_ROWS * D / 256), dim3(256), 0, stream>>>(node, out0);
    // 8) attribute features -> out (f32)
    k_att<<<dim3(NB * N_OBJ), dim3(256), 0, stream>>>(ssg_obj, ssg_att, PRE, ba, out0);
    // 9) masks -> out (f32)
    k_mask<<<dim3((NB * 3072 + 255) / 256), dim3(256), 0, stream>>>(ssg_rel, ssg_obj, ssg_att, out1);
}